// Round 6
// baseline (183.953 us; speedup 1.0000x reference)
//
#include <hip/hip_runtime.h>
#include <math.h>

#define NN 8192
#define CC 256
#define OO 64
#define NB 256     // grid blocks (== CUs, 1 block/CU forced by 64 KB LDS)
#define NT 1024    // threads per block

// ---- workspace layout (float offsets) ----
#define OFF_SEQ   0
#define OFF_F1    524288
#define OFF_F2    532480
#define OFF_E1    540672
#define OFF_E1S   548864
#define OFF_EF2   557056
#define OFF_EF2S  565248
#define OFF_KEYS  573440   /* u64[2*NN] = 32768 floats */
#define OFF_RANK2 606208
#define OFF_INV   614400
#define OFF_S1    622592
#define OFF_SE1   630784
#define OFF_SE1S  638976
#define OFF_F2S   647168
#define OFF_BS    655360
#define OFF_ES    663552
#define OFF_TU    671744
#define OFF_TV    688128
#define OFF_PU    704512   /* (NN+1)*64 */
#define OFF_PV    1228864
#define OFF_BAR   1753216  /* 8 x u32 barrier counters */

union SMem {
  float4 w4[4096];                                // P1: W1^T, 64 KB
  unsigned long long sk[NN];                      // P2: staged keys (tail-reused as int cnts)
  struct { float preA[NN]; float preB[NN]; } p4;  // P4: prefix tables, 64 KB
  struct { float pu[16][72]; float pv[16][72]; } p5;
  struct { float bu[64]; float bv[64]; } p6;
  float f2sl[NN];                                 // P7: sorted f2, 32 KB
};

__device__ __forceinline__ void gridbar(unsigned* cnt) {
  __syncthreads();
  if (threadIdx.x == 0) {
    __threadfence();                       // release: make my writes visible device-wide
    atomicAdd(cnt, 1u);
    while (__hip_atomic_load(cnt, __ATOMIC_ACQUIRE, __HIP_MEMORY_SCOPE_AGENT) < (unsigned)NB)
      __builtin_amdgcn_s_sleep(2);
  }
  __syncthreads();
}

__global__ void __launch_bounds__(NT, 4) k_all(
    const float* __restrict__ x, const float* __restrict__ W1,
    const float* __restrict__ b1, const float* __restrict__ a1,
    const float* __restrict__ ba1, const float* __restrict__ a2,
    const float* __restrict__ ba2, float* __restrict__ ws,
    float* __restrict__ out)
{
  __shared__ SMem sm;
  const int t = threadIdx.x;
  const int lane = t & 63;
  const int wv = t >> 6;
  const int b = blockIdx.x;

  float* __restrict__ seq  = ws + OFF_SEQ;
  float* __restrict__ f1   = ws + OFF_F1;
  float* __restrict__ f2   = ws + OFF_F2;
  float* __restrict__ E1   = ws + OFF_E1;
  float* __restrict__ E1s  = ws + OFF_E1S;
  float* __restrict__ eF2  = ws + OFF_EF2;
  float* __restrict__ eF2s = ws + OFF_EF2S;
  unsigned long long* __restrict__ keys = (unsigned long long*)(ws + OFF_KEYS);
  int* __restrict__ rank2 = (int*)(ws + OFF_RANK2);
  int* __restrict__ inv   = (int*)(ws + OFF_INV);
  float* __restrict__ s1   = ws + OFF_S1;
  float* __restrict__ se1  = ws + OFF_SE1;
  float* __restrict__ se1s = ws + OFF_SE1S;
  float* __restrict__ f2s  = ws + OFF_F2S;
  float* __restrict__ Bs   = ws + OFF_BS;
  float* __restrict__ Es   = ws + OFF_ES;
  float* __restrict__ TU   = ws + OFF_TU;
  float* __restrict__ TV   = ws + OFF_TV;
  float* __restrict__ PU   = ws + OFF_PU;
  float* __restrict__ PV   = ws + OFF_PV;
  unsigned* __restrict__ bar = (unsigned*)(ws + OFF_BAR);

  // ================= P1: GEMM + f1/f2 + exp tables + sortable keys =================
  for (int q = t; q < 4096; q += NT) {
    const float4 gv = ((const float4*)W1)[q];        // q = o*64 + c4
    sm.w4[(q & 63)*64 + (q >> 6)] = gv;              // [c4][o]
  }
  __syncthreads();
  if (wv < 8) {
    const int r0 = b*32 + wv*4;
    const float* xb = x + (size_t)__builtin_amdgcn_readfirstlane(r0) * CC;
    float ac0 = 0.f, ac1 = 0.f, ac2 = 0.f, ac3 = 0.f;
    for (int c4 = 0; c4 < 64; ++c4) {
      const float4 wvec = sm.w4[c4*64 + lane];
      const float4 x0 = ((const float4*)(xb         ))[c4];
      const float4 x1 = ((const float4*)(xb +    CC))[c4];
      const float4 x2 = ((const float4*)(xb + 2*CC))[c4];
      const float4 x3 = ((const float4*)(xb + 3*CC))[c4];
      ac0 = fmaf(x0.x, wvec.x, ac0); ac0 = fmaf(x0.y, wvec.y, ac0);
      ac0 = fmaf(x0.z, wvec.z, ac0); ac0 = fmaf(x0.w, wvec.w, ac0);
      ac1 = fmaf(x1.x, wvec.x, ac1); ac1 = fmaf(x1.y, wvec.y, ac1);
      ac1 = fmaf(x1.z, wvec.z, ac1); ac1 = fmaf(x1.w, wvec.w, ac1);
      ac2 = fmaf(x2.x, wvec.x, ac2); ac2 = fmaf(x2.y, wvec.y, ac2);
      ac2 = fmaf(x2.z, wvec.z, ac2); ac2 = fmaf(x2.w, wvec.w, ac2);
      ac3 = fmaf(x3.x, wvec.x, ac3); ac3 = fmaf(x3.y, wvec.y, ac3);
      ac3 = fmaf(x3.z, wvec.z, ac3); ac3 = fmaf(x3.w, wvec.w, ac3);
    }
    const float bb = b1[lane];
    const float v0 = ac0 + bb, v1 = ac1 + bb, v2 = ac2 + bb, v3 = ac3 + bb;
    seq[(size_t)(r0+0)*OO + lane] = v0;
    seq[(size_t)(r0+1)*OO + lane] = v1;
    seq[(size_t)(r0+2)*OO + lane] = v2;
    seq[(size_t)(r0+3)*OO + lane] = v3;
    const float A1 = a1[lane], A2 = a2[lane];
    float q10 = v0*A1, q11 = v1*A1, q12 = v2*A1, q13 = v3*A1;
    float q20 = v0*A2, q21 = v1*A2, q22 = v2*A2, q23 = v3*A2;
    for (int d = 1; d < 64; d <<= 1) {
      q10 += __shfl_xor(q10, d, 64); q11 += __shfl_xor(q11, d, 64);
      q12 += __shfl_xor(q12, d, 64); q13 += __shfl_xor(q13, d, 64);
      q20 += __shfl_xor(q20, d, 64); q21 += __shfl_xor(q21, d, 64);
      q22 += __shfl_xor(q22, d, 64); q23 += __shfl_xor(q23, d, 64);
    }
    if (lane < 4) {
      const float t1 = (lane==0?q10: lane==1?q11: lane==2?q12: q13) + ba1[0];
      const float t2 = (lane==0?q20: lane==1?q21: lane==2?q22: q23) + ba2[0];
      const int r = r0 + lane;
      f1[r] = t1; E1[r] = expf(t1); E1s[r] = expf(0.01f*t1);
      f2[r] = t2; eF2[r] = expf(t2); eF2s[r] = expf(0.01f*t2);
      unsigned u1 = __float_as_uint(t1);
      u1 = (u1 & 0x80000000u) ? ~u1 : (u1 | 0x80000000u);
      keys[r] = ((unsigned long long)u1 << 32) | (unsigned)r;
      unsigned u2 = __float_as_uint(t2);
      u2 = (u2 & 0x80000000u) ? ~u2 : (u2 | 0x80000000u);
      keys[NN + r] = ((unsigned long long)u2 << 32) | (unsigned)r;
    }
  }
  gridbar(bar + 0);

  // ================= P2: rank counting + sorted scatters =================
  {
    const int arr = b >> 7;                 // 0: f1 keys, 1: f2 keys
    const int jb  = (b & 127) * 64;
    const unsigned long long* kb = keys + (size_t)arr * NN;
    for (int q = t; q < NN/2; q += NT)
      ((ulonglong2*)sm.sk)[q] = ((const ulonglong2*)kb)[q];
    __syncthreads();
    const unsigned long long my = sm.sk[jb + lane];
    const ulonglong2* s2 = ((const ulonglong2*)sm.sk) + wv*256;  // this wave's 512-key chunk
    int cnt = 0;
#pragma unroll 8
    for (int q = 0; q < 256; ++q) {
      const ulonglong2 kk = s2[q];
      cnt += (kk.x < my) ? 1 : 0;
      cnt += (kk.y < my) ? 1 : 0;
    }
    __syncthreads();                        // done reading keys; reuse LDS for counts
    ((int*)sm.sk)[wv*64 + lane] = cnt;
    __syncthreads();
    if (t < 64) {
      int r = 0;
#pragma unroll
      for (int q2 = 0; q2 < 16; ++q2) r += ((int*)sm.sk)[q2*64 + t];
      const int i = jb + t;
      if (arr == 0) {
        s1[r] = f1[i]; se1[r] = E1[i]; se1s[r] = E1s[i];
      } else {
        rank2[i] = r; inv[r] = i; f2s[r] = f2[i];
      }
    }
  }
  gridbar(bar + 1);

  // ================= P4: dual prefix scan (in-LDS) + per-j D -> Bs/Es =================
  {
    const float4 ea = ((const float4*)se1 )[t*2];
    const float4 eb = ((const float4*)se1 )[t*2+1];
    const float4 fa = ((const float4*)se1s)[t*2];
    const float4 fb = ((const float4*)se1s)[t*2+1];
    const float sA = ((ea.x+ea.y)+(ea.z+ea.w)) + ((eb.x+eb.y)+(eb.z+eb.w));
    const float sB = ((fa.x+fa.y)+(fa.z+fa.w)) + ((fb.x+fb.y)+(fb.z+fb.w));
    float iA = sA, iB = sB;
    for (int d = 1; d < 64; d <<= 1) {
      const float uA = __shfl_up(iA, d, 64);
      const float uB = __shfl_up(iB, d, 64);
      if (lane >= d) { iA += uA; iB += uB; }
    }
    if (lane == 63) { sm.p4.preA[wv] = iA; sm.p4.preB[wv] = iB; }  // temp wave partials
    __syncthreads();
    float baseA = 0.f, baseB = 0.f, T1 = 0.f, T1s = 0.f;
#pragma unroll
    for (int q = 0; q < 16; ++q) {
      const float wa = sm.p4.preA[q], wb = sm.p4.preB[q];
      T1 += wa; T1s += wb;
      if (q < wv) { baseA += wa; baseB += wb; }
    }
    __syncthreads();                        // partials consumed; overwrite with prefixes
    float run = baseA + iA - sA;
    float4 ov;
    ov.x = run; run += ea.x; ov.y = run; run += ea.y;
    ov.z = run; run += ea.z; ov.w = run; run += ea.w;
    ((float4*)sm.p4.preA)[t*2] = ov;
    ov.x = run; run += eb.x; ov.y = run; run += eb.y;
    ov.z = run; run += eb.z; ov.w = run; run += eb.w;
    ((float4*)sm.p4.preA)[t*2+1] = ov;
    run = baseB + iB - sB;
    ov.x = run; run += fa.x; ov.y = run; run += fa.y;
    ov.z = run; run += fa.z; ov.w = run; run += fa.w;
    ((float4*)sm.p4.preB)[t*2] = ov;
    ov.x = run; run += fb.x; ov.y = run; run += fb.y;
    ov.z = run; run += fb.z; ov.w = run; run += fb.w;
    ((float4*)sm.p4.preB)[t*2+1] = ov;
    __syncthreads();
    if (t < 32) {
      const int j = b*32 + t;
      const float tgt = -f2[j];
      int pos = 0;
#pragma unroll
      for (int s = NN; s; s >>= 1) {
        const int c = pos + s;
        if (c <= NN && s1[c-1] < tgt) pos = c;   // probe global s1 (L2-resident)
      }
      const float pA = (pos < NN) ? sm.p4.preA[pos] : T1;
      const float pB = (pos < NN) ? sm.p4.preB[pos] : T1s;
      const float A  = T1 - pA;
      const float e2 = eF2[j], e2s = eF2s[j];
      const float D = fmaf(A, e2, pB * e2s);
      const int r2 = rank2[j];
      Bs[r2] = e2 / D;
      Es[r2] = e2s / D;
    }
  }
  gridbar(bar + 2);

  // ================= P5: per-chunk (32 sorted rows) column totals TU/TV =================
  {
    float su = 0.f, sv = 0.f;
#pragma unroll
    for (int m = 2*wv; m < 2*wv + 2; ++m) {
      const int kk = b*32 + m;
      const int jj = inv[kk];
      const float s = seq[(size_t)jj*OO + lane];
      su = fmaf(Bs[kk], s, su);
      sv = fmaf(Es[kk], s, sv);
    }
    sm.p5.pu[wv][lane] = su; sm.p5.pv[wv][lane] = sv;
    __syncthreads();
    if (wv == 0) {
      float r = 0.f;
#pragma unroll
      for (int q = 0; q < 16; ++q) r += sm.p5.pu[q][lane];
      TU[b*64 + lane] = r;
    } else if (wv == 1) {
      float r = 0.f;
#pragma unroll
      for (int q = 0; q < 16; ++q) r += sm.p5.pv[q][lane];
      TV[b*64 + lane] = r;
    }
  }
  gridbar(bar + 3);

  // ================= P6: prefix tables PU/PV [NN+1][OO] =================
  {
    if (wv == 0) {
      float r = 0.f;
#pragma unroll 8
      for (int c = 0; c < b; ++c) r += TU[c*64 + lane];
      sm.p6.bu[lane] = r;
    } else if (wv == 1) {
      float r = 0.f;
#pragma unroll 8
      for (int c = 0; c < b; ++c) r += TV[c*64 + lane];
      sm.p6.bv[lane] = r;
    }
    __syncthreads();
    float ru = sm.p6.bu[lane], rv = sm.p6.bv[lane];
    for (int m2 = 0; m2 < 2*wv; ++m2) {
      const int kk = b*32 + m2;
      const float s = seq[(size_t)inv[kk]*OO + lane];
      ru = fmaf(Bs[kk], s, ru); rv = fmaf(Es[kk], s, rv);
    }
    const int row0 = b*32 + 2*wv;
    PU[(size_t)row0*OO + lane] = ru; PV[(size_t)row0*OO + lane] = rv;
    {
      const float s = seq[(size_t)inv[row0]*OO + lane];
      ru = fmaf(Bs[row0], s, ru); rv = fmaf(Es[row0], s, rv);
    }
    PU[(size_t)(row0+1)*OO + lane] = ru; PV[(size_t)(row0+1)*OO + lane] = rv;
    if (b == NB-1 && wv == 15) {           // grand-total row
      const int kk = row0 + 1;
      const float s = seq[(size_t)inv[kk]*OO + lane];
      ru = fmaf(Bs[kk], s, ru); rv = fmaf(Es[kk], s, rv);
      PU[(size_t)NN*OO + lane] = ru; PV[(size_t)NN*OO + lane] = rv;
    }
  }
  gridbar(bar + 4);

  // ================= P7: final combine + ELU =================
  {
    for (int q = t; q < NN/4; q += NT)
      ((float4*)sm.f2sl)[q] = ((const float4*)f2s)[q];
    __syncthreads();
    const float utot = PU[(size_t)NN*OO + lane];
#pragma unroll
    for (int rr = 0; rr < 2; ++rr) {
      const int i = b*32 + 2*wv + rr;
      const float tgt = -f1[i];
      int pos = 0;
#pragma unroll
      for (int s = NN; s; s >>= 1) {
        const int c = pos + s;
        if (c <= NN && sm.f2sl[c-1] < tgt) pos = c;
      }
      const float pu = PU[(size_t)pos*OO + lane];
      const float pv = PV[(size_t)pos*OO + lane];
      const float ret = E1[i]*(utot - pu) + E1s[i]*pv;
      out[(size_t)i*OO + lane] = (ret > 0.f) ? ret : expm1f(ret);
    }
  }
}

extern "C" void kernel_launch(void* const* d_in, const int* in_sizes, int n_in,
                              void* d_out, int out_size, void* d_ws, size_t ws_size,
                              hipStream_t stream)
{
  (void)in_sizes; (void)n_in; (void)out_size; (void)ws_size;
  const float* x   = (const float*)d_in[0];
  const float* W1  = (const float*)d_in[1];
  const float* b1  = (const float*)d_in[2];
  const float* a1  = (const float*)d_in[3];
  const float* ba1 = (const float*)d_in[4];
  const float* a2  = (const float*)d_in[5];
  const float* ba2 = (const float*)d_in[6];
  float* ws  = (float*)d_ws;
  float* out = (float*)d_out;

  // zero the 5 barrier counters (tiny fill node, capture-safe — verified round 3)
  hipMemsetAsync(ws + OFF_BAR, 0, 8*sizeof(unsigned), stream);
  hipLaunchKernelGGL(k_all, dim3(NB), dim3(NT), 0, stream,
                     x, W1, b1, a1, ba1, a2, ba2, ws, out);
}

// Round 7
// 83.905 us; speedup vs baseline: 2.1924x; 2.1924x over previous
//
#include <hip/hip_runtime.h>
#include <math.h>

#define NN 8192
#define CC 256
#define OO 64

// ============ K1: GEMM (W1 -> LDS transposed) + f1/f2 + exp tables + sortable keys ============
__global__ __launch_bounds__(256) void k_gemm(
    const float* __restrict__ x, const float* __restrict__ W1,
    const float* __restrict__ b1, const float* __restrict__ a1,
    const float* __restrict__ ba1, const float* __restrict__ a2,
    const float* __restrict__ ba2,
    float* __restrict__ seq,
    float* __restrict__ f1, float* __restrict__ f2,
    float* __restrict__ E1, float* __restrict__ E1s,
    float* __restrict__ eF2, float* __restrict__ eF2s,
    unsigned long long* __restrict__ keys /* [2][NN] */)
{
  __shared__ float w_lds[64][66];
  const int t = threadIdx.x;
  const int p = t & 31;             // col pair: o = 2p, 2p+1
  const int g = t >> 5;             // 0..7 row group
  const int r0 = blockIdx.x*16 + g*2;
  const int r1 = r0 + 1;
  float c00 = 0.f, c01 = 0.f, c10 = 0.f, c11 = 0.f;
  for (int ct = 0; ct < 4; ++ct) {
    __syncthreads();
    for (int idx = t; idx < 4096; idx += 256) {
      const int o = idx >> 6, cc = idx & 63;
      w_lds[cc][o] = W1[o*CC + ct*64 + cc];
    }
    __syncthreads();
    const float* xr0 = x + (size_t)r0*CC + ct*64;
    const float* xr1 = x + (size_t)r1*CC + ct*64;
#pragma unroll 4
    for (int c = 0; c < 64; c += 4) {
      const float4 xa = *(const float4*)(xr0 + c);
      const float4 xb = *(const float4*)(xr1 + c);
      const float2 w0 = *(const float2*)&w_lds[c+0][2*p];
      const float2 w1 = *(const float2*)&w_lds[c+1][2*p];
      const float2 w2 = *(const float2*)&w_lds[c+2][2*p];
      const float2 w3 = *(const float2*)&w_lds[c+3][2*p];
      c00 = fmaf(xa.x, w0.x, c00); c00 = fmaf(xa.y, w1.x, c00);
      c00 = fmaf(xa.z, w2.x, c00); c00 = fmaf(xa.w, w3.x, c00);
      c01 = fmaf(xa.x, w0.y, c01); c01 = fmaf(xa.y, w1.y, c01);
      c01 = fmaf(xa.z, w2.y, c01); c01 = fmaf(xa.w, w3.y, c01);
      c10 = fmaf(xb.x, w0.x, c10); c10 = fmaf(xb.y, w1.x, c10);
      c10 = fmaf(xb.z, w2.x, c10); c10 = fmaf(xb.w, w3.x, c10);
      c11 = fmaf(xb.x, w0.y, c11); c11 = fmaf(xb.y, w1.y, c11);
      c11 = fmaf(xb.z, w2.y, c11); c11 = fmaf(xb.w, w3.y, c11);
    }
  }
  const float2 B2 = *(const float2*)&b1[2*p];
  const float v00 = c00 + B2.x, v01 = c01 + B2.y;
  const float v10 = c10 + B2.x, v11 = c11 + B2.y;
  *(float2*)&seq[(size_t)r0*OO + 2*p] = make_float2(v00, v01);
  *(float2*)&seq[(size_t)r1*OO + 2*p] = make_float2(v10, v11);
  const float2 A1 = *(const float2*)&a1[2*p];
  const float2 A2 = *(const float2*)&a2[2*p];
  float p1_0 = v00*A1.x + v01*A1.y;
  float p2_0 = v00*A2.x + v01*A2.y;
  float p1_1 = v10*A1.x + v11*A1.y;
  float p2_1 = v10*A2.x + v11*A2.y;
#pragma unroll
  for (int d = 1; d < 32; d <<= 1) {
    p1_0 += __shfl_xor(p1_0, d, 64);
    p2_0 += __shfl_xor(p2_0, d, 64);
    p1_1 += __shfl_xor(p1_1, d, 64);
    p2_1 += __shfl_xor(p2_1, d, 64);
  }
  if (p == 0) {
    const float bba1 = ba1[0], bba2 = ba2[0];
    const float t1a = p1_0 + bba1, t2a = p2_0 + bba2;
    const float t1b = p1_1 + bba1, t2b = p2_1 + bba2;
    f1[r0] = t1a; E1[r0] = expf(t1a); E1s[r0] = expf(0.01f*t1a);
    f2[r0] = t2a; eF2[r0] = expf(t2a); eF2s[r0] = expf(0.01f*t2a);
    f1[r1] = t1b; E1[r1] = expf(t1b); E1s[r1] = expf(0.01f*t1b);
    f2[r1] = t2b; eF2[r1] = expf(t2b); eF2s[r1] = expf(0.01f*t2b);
    unsigned u;
    u = __float_as_uint(t1a); u = (u & 0x80000000u) ? ~u : (u | 0x80000000u);
    keys[r0] = ((unsigned long long)u << 32) | (unsigned)r0;
    u = __float_as_uint(t1b); u = (u & 0x80000000u) ? ~u : (u | 0x80000000u);
    keys[r1] = ((unsigned long long)u << 32) | (unsigned)r1;
    u = __float_as_uint(t2a); u = (u & 0x80000000u) ? ~u : (u | 0x80000000u);
    keys[NN + r0] = ((unsigned long long)u << 32) | (unsigned)r0;
    u = __float_as_uint(t2b); u = (u & 0x80000000u) ? ~u : (u | 0x80000000u);
    keys[NN + r1] = ((unsigned long long)u << 32) | (unsigned)r1;
  }
}

// ============ K2: rank counting (SGPR-broadcast key scan) + sorted scatters ============
// grid 256 x 1024: p = b>>7 selects key array; block handles 64 j's; wave w scans keys[w*512..+512)
__global__ __launch_bounds__(1024) void k_rank(
    const unsigned long long* __restrict__ keys,
    const float* __restrict__ f1, const float* __restrict__ E1,
    const float* __restrict__ E1s, const float* __restrict__ f2,
    float* __restrict__ s1, float* __restrict__ se1, float* __restrict__ se1s,
    float* __restrict__ f2s, int* __restrict__ rank2, int* __restrict__ inv)
{
  __shared__ int part[16][64];
  const int t = threadIdx.x;
  const int lane = t & 63, wv = t >> 6;
  const int p = blockIdx.x >> 7;
  const int jb = (blockIdx.x & 127) * 64;
  const unsigned long long* kb = keys + (size_t)p * NN;
  const unsigned long long my = kb[jb + lane];
  const unsigned long long* cb = kb + wv*512;   // wave-uniform base -> s_load
  int cnt = 0;
#pragma unroll 16
  for (int q = 0; q < 512; ++q)
    cnt += (cb[q] < my) ? 1 : 0;
  part[wv][lane] = cnt;
  __syncthreads();
  if (t < 64) {
    int r = 0;
#pragma unroll
    for (int q = 0; q < 16; ++q) r += part[q][t];
    const int i = jb + t;
    if (p == 0) {
      s1[r] = f1[i]; se1[r] = E1[i]; se1s[r] = E1s[i];
    } else {
      rank2[i] = r; inv[r] = i; f2s[r] = f2[i];
    }
  }
}

// ============ K3: per-block redundant chunk-prefix of sorted exp tables + D_j -> Bs/Es ============
// grid 256 x 1024: block b handles j in [32b, 32b+32)
__global__ __launch_bounds__(1024) void k_D(
    const float* __restrict__ se1, const float* __restrict__ se1s,
    const float* __restrict__ s1g, const float* __restrict__ f2,
    const float* __restrict__ eF2, const float* __restrict__ eF2s,
    const int* __restrict__ rank2,
    float* __restrict__ Bs, float* __restrict__ Es)
{
  __shared__ float s1l[NN];          // 32 KB
  __shared__ float csA[256], csB[256];
  __shared__ float csEA[257], csEB[257];
  const int t = threadIdx.x;
  // load + per-thread 8-sums + stage s1
  const float4 a0 = ((const float4*)se1 )[t*2];
  const float4 a1v = ((const float4*)se1 )[t*2+1];
  const float4 b0 = ((const float4*)se1s)[t*2];
  const float4 b1v = ((const float4*)se1s)[t*2+1];
  ((float4*)s1l)[t*2]   = ((const float4*)s1g)[t*2];
  ((float4*)s1l)[t*2+1] = ((const float4*)s1g)[t*2+1];
  float sa = ((a0.x+a0.y)+(a0.z+a0.w)) + ((a1v.x+a1v.y)+(a1v.z+a1v.w));
  float sb = ((b0.x+b0.y)+(b0.z+b0.w)) + ((b1v.x+b1v.y)+(b1v.z+b1v.w));
  sa += __shfl_xor(sa, 1, 64); sb += __shfl_xor(sb, 1, 64);
  sa += __shfl_xor(sa, 2, 64); sb += __shfl_xor(sb, 2, 64);
  if ((t & 3) == 0) { csA[t>>2] = sa; csB[t>>2] = sb; }   // chunk(32) sums
  __syncthreads();
  // Hillis-Steele inclusive scan over 256 chunks (both arrays)
  for (int d = 1; d < 256; d <<= 1) {
    float pa = 0.f, pb = 0.f;
    if (t >= d && t < 256) { pa = csA[t-d]; pb = csB[t-d]; }
    __syncthreads();
    if (t < 256) { csA[t] += pa; csB[t] += pb; }
    __syncthreads();
  }
  if (t < 256) { csEA[t+1] = csA[t]; csEB[t+1] = csB[t]; }
  if (t == 0)  { csEA[0] = 0.f; csEB[0] = 0.f; }
  __syncthreads();
  // per-j: branchless search in LDS, tail sum via half-wave, D -> Bs/Es
  const int wv = t >> 6, lane = t & 63;
  const int half = lane >> 5, m = lane & 31;
  const int j = blockIdx.x*32 + 2*wv + half;
  const float tgt = -f2[j];
  int pos = 0;
#pragma unroll
  for (int s = NN; s; s >>= 1) {
    const int c = pos + s;
    if (c <= NN && s1l[c-1] < tgt) pos = c;
  }
  const int base = pos & ~31, cnt = pos & 31;
  float ta = 0.f, tb = 0.f;
  if (m < cnt) { ta = se1[base+m]; tb = se1s[base+m]; }
#pragma unroll
  for (int d = 1; d < 32; d <<= 1) {
    ta += __shfl_xor(ta, d, 64);
    tb += __shfl_xor(tb, d, 64);
  }
  if (m == 0) {
    const float PreA = csEA[pos>>5] + ta;
    const float PreB = csEB[pos>>5] + tb;
    const float T1 = csEA[256];
    const float e2 = eF2[j], e2s = eF2s[j];
    const float D = fmaf(T1 - PreA, e2, PreB * e2s);
    const int r2 = rank2[j];
    Bs[r2] = e2 / D;
    Es[r2] = e2s / D;
  }
}

// ============ K4: chunk(32) column totals TU/TV ============  grid 256 x 64
__global__ __launch_bounds__(64) void k_tuv(
    const float* __restrict__ seq, const int* __restrict__ inv,
    const float* __restrict__ Bs, const float* __restrict__ Es,
    float* __restrict__ TU, float* __restrict__ TV)
{
  const int c = blockIdx.x, o = threadIdx.x;
  float su = 0.f, sv = 0.f;
#pragma unroll 8
  for (int m = 0; m < 32; ++m) {
    const int kk = c*32 + m;
    const float s = seq[(size_t)inv[kk]*OO + o];
    su = fmaf(Bs[kk], s, su);
    sv = fmaf(Es[kk], s, sv);
  }
  TU[c*64 + o] = su;
  TV[c*64 + o] = sv;
}

// ============ K5: PU/PV prefix rows (base = redundant TU/TV prefix) ============ grid 256 x 128
__global__ __launch_bounds__(128) void k_apply(
    const float* __restrict__ seq, const int* __restrict__ inv,
    const float* __restrict__ Bs, const float* __restrict__ Es,
    const float* __restrict__ TU, const float* __restrict__ TV,
    float* __restrict__ PU, float* __restrict__ PV)
{
  const int b = blockIdx.x;
  const int h = threadIdx.x >> 6, o = threadIdx.x & 63;
  const float* __restrict__ S = h ? Es : Bs;
  const float* __restrict__ T = h ? TV : TU;
  float* __restrict__ dst     = h ? PV : PU;
  float r = 0.f;
#pragma unroll 8
  for (int c = 0; c < b; ++c) r += T[c*64 + o];
#pragma unroll 4
  for (int k = 0; k < 32; ++k) {
    const int kk = b*32 + k;
    dst[(size_t)kk*OO + o] = r;
    r = fmaf(S[kk], seq[(size_t)inv[kk]*OO + o], r);
  }
  if (b == 255) dst[(size_t)NN*OO + o] = r;   // grand total row
}

// ============ K6: final combine + ELU (search in LDS-staged f2s) ============ grid 256 x 1024
__global__ __launch_bounds__(1024) void k_final(
    const float* __restrict__ f1, const float* __restrict__ E1,
    const float* __restrict__ E1s, const float* __restrict__ f2s,
    const float* __restrict__ PU, const float* __restrict__ PV,
    float* __restrict__ out)
{
  __shared__ float f2sl[NN];
  const int t = threadIdx.x;
  ((float4*)f2sl)[t*2]   = ((const float4*)f2s)[t*2];
  ((float4*)f2sl)[t*2+1] = ((const float4*)f2s)[t*2+1];
  __syncthreads();
  const int wv = t >> 6, lane = t & 63;
  const float utot = PU[(size_t)NN*OO + lane];
#pragma unroll
  for (int rr = 0; rr < 2; ++rr) {
    const int i = blockIdx.x*32 + 2*wv + rr;
    const float tgt = -f1[i];
    int pos = 0;
#pragma unroll
    for (int s = NN; s; s >>= 1) {
      const int c = pos + s;
      if (c <= NN && f2sl[c-1] < tgt) pos = c;
    }
    const float pu = PU[(size_t)pos*OO + lane];
    const float pv = PV[(size_t)pos*OO + lane];
    const float ret = E1[i]*(utot - pu) + E1s[i]*pv;
    out[(size_t)i*OO + lane] = (ret > 0.f) ? ret : expm1f(ret);
  }
}

extern "C" void kernel_launch(void* const* d_in, const int* in_sizes, int n_in,
                              void* d_out, int out_size, void* d_ws, size_t ws_size,
                              hipStream_t stream)
{
  (void)in_sizes; (void)n_in; (void)out_size; (void)ws_size;
  const float* x   = (const float*)d_in[0];
  const float* W1  = (const float*)d_in[1];
  const float* b1  = (const float*)d_in[2];
  const float* a1  = (const float*)d_in[3];
  const float* ba1 = (const float*)d_in[4];
  const float* a2  = (const float*)d_in[5];
  const float* ba2 = (const float*)d_in[6];
  float* out = (float*)d_out;

  float* w = (float*)d_ws;
  size_t off = 0;
  auto alloc = [&](size_t n) { float* p = w + off; off += (n + 63) & ~(size_t)63; return p; };
  float* seq  = alloc((size_t)NN*OO);
  float* f1   = alloc(NN);
  float* f2   = alloc(NN);
  float* E1   = alloc(NN);
  float* E1s  = alloc(NN);
  float* eF2  = alloc(NN);
  float* eF2s = alloc(NN);
  unsigned long long* keys = (unsigned long long*)alloc((size_t)4*NN);
  int*   rank2 = (int*)alloc(NN);
  int*   inv   = (int*)alloc(NN);
  float* s1   = alloc(NN);
  float* se1  = alloc(NN);
  float* se1s = alloc(NN);
  float* f2s  = alloc(NN);
  float* Bs   = alloc(NN);
  float* Es   = alloc(NN);
  float* TU   = alloc(256*64);
  float* TV   = alloc(256*64);
  float* PU   = alloc((size_t)(NN+1)*OO);
  float* PV   = alloc((size_t)(NN+1)*OO);

  k_gemm<<<512, 256, 0, stream>>>(x, W1, b1, a1, ba1, a2, ba2,
                                  seq, f1, f2, E1, E1s, eF2, eF2s, keys);
  k_rank<<<256, 1024, 0, stream>>>(keys, f1, E1, E1s, f2,
                                   s1, se1, se1s, f2s, rank2, inv);
  k_D<<<256, 1024, 0, stream>>>(se1, se1s, s1, f2, eF2, eF2s, rank2, Bs, Es);
  k_tuv<<<256, 64, 0, stream>>>(seq, inv, Bs, Es, TU, TV);
  k_apply<<<256, 128, 0, stream>>>(seq, inv, Bs, Es, TU, TV, PU, PV);
  k_final<<<256, 1024, 0, stream>>>(f1, E1, E1s, f2s, PU, PV, out);
}

// Round 8
// 68.718 us; speedup vs baseline: 2.6769x; 1.2210x over previous
//
#include <hip/hip_runtime.h>
#include <math.h>

#define NN 8192
#define CC 256
#define OO 64
#define JW 8      // j's per wave in k_rank

// ============ K1: GEMM (W1 -> LDS transposed) + f1/f2 + exp tables + sortable keys ============
__global__ __launch_bounds__(256) void k_gemm(
    const float* __restrict__ x, const float* __restrict__ W1,
    const float* __restrict__ b1, const float* __restrict__ a1,
    const float* __restrict__ ba1, const float* __restrict__ a2,
    const float* __restrict__ ba2,
    float* __restrict__ seq,
    float* __restrict__ f1, float* __restrict__ f2,
    float* __restrict__ E1, float* __restrict__ E1s,
    float* __restrict__ eF2, float* __restrict__ eF2s,
    unsigned long long* __restrict__ keys /* [2][NN] */)
{
  __shared__ float w_lds[64][66];
  const int t = threadIdx.x;
  const int p = t & 31;             // col pair: o = 2p, 2p+1
  const int g = t >> 5;             // 0..7 row group
  const int r0 = blockIdx.x*16 + g*2;
  const int r1 = r0 + 1;
  float c00 = 0.f, c01 = 0.f, c10 = 0.f, c11 = 0.f;
  for (int ct = 0; ct < 4; ++ct) {
    __syncthreads();
    for (int idx = t; idx < 4096; idx += 256) {
      const int o = idx >> 6, cc = idx & 63;
      w_lds[cc][o] = W1[o*CC + ct*64 + cc];
    }
    __syncthreads();
    const float* xr0 = x + (size_t)r0*CC + ct*64;
    const float* xr1 = x + (size_t)r1*CC + ct*64;
#pragma unroll 4
    for (int c = 0; c < 64; c += 4) {
      const float4 xa = *(const float4*)(xr0 + c);
      const float4 xb = *(const float4*)(xr1 + c);
      const float2 w0 = *(const float2*)&w_lds[c+0][2*p];
      const float2 w1 = *(const float2*)&w_lds[c+1][2*p];
      const float2 w2 = *(const float2*)&w_lds[c+2][2*p];
      const float2 w3 = *(const float2*)&w_lds[c+3][2*p];
      c00 = fmaf(xa.x, w0.x, c00); c00 = fmaf(xa.y, w1.x, c00);
      c00 = fmaf(xa.z, w2.x, c00); c00 = fmaf(xa.w, w3.x, c00);
      c01 = fmaf(xa.x, w0.y, c01); c01 = fmaf(xa.y, w1.y, c01);
      c01 = fmaf(xa.z, w2.y, c01); c01 = fmaf(xa.w, w3.y, c01);
      c10 = fmaf(xb.x, w0.x, c10); c10 = fmaf(xb.y, w1.x, c10);
      c10 = fmaf(xb.z, w2.x, c10); c10 = fmaf(xb.w, w3.x, c10);
      c11 = fmaf(xb.x, w0.y, c11); c11 = fmaf(xb.y, w1.y, c11);
      c11 = fmaf(xb.z, w2.y, c11); c11 = fmaf(xb.w, w3.y, c11);
    }
  }
  const float2 B2 = *(const float2*)&b1[2*p];
  const float v00 = c00 + B2.x, v01 = c01 + B2.y;
  const float v10 = c10 + B2.x, v11 = c11 + B2.y;
  *(float2*)&seq[(size_t)r0*OO + 2*p] = make_float2(v00, v01);
  *(float2*)&seq[(size_t)r1*OO + 2*p] = make_float2(v10, v11);
  const float2 A1 = *(const float2*)&a1[2*p];
  const float2 A2 = *(const float2*)&a2[2*p];
  float p1_0 = v00*A1.x + v01*A1.y;
  float p2_0 = v00*A2.x + v01*A2.y;
  float p1_1 = v10*A1.x + v11*A1.y;
  float p2_1 = v10*A2.x + v11*A2.y;
#pragma unroll
  for (int d = 1; d < 32; d <<= 1) {
    p1_0 += __shfl_xor(p1_0, d, 64);
    p2_0 += __shfl_xor(p2_0, d, 64);
    p1_1 += __shfl_xor(p1_1, d, 64);
    p2_1 += __shfl_xor(p2_1, d, 64);
  }
  if (p == 0) {
    const float bba1 = ba1[0], bba2 = ba2[0];
    const float t1a = p1_0 + bba1, t2a = p2_0 + bba2;
    const float t1b = p1_1 + bba1, t2b = p2_1 + bba2;
    f1[r0] = t1a; E1[r0] = expf(t1a); E1s[r0] = expf(0.01f*t1a);
    f2[r0] = t2a; eF2[r0] = expf(t2a); eF2s[r0] = expf(0.01f*t2a);
    f1[r1] = t1b; E1[r1] = expf(t1b); E1s[r1] = expf(0.01f*t1b);
    f2[r1] = t2b; eF2[r1] = expf(t2b); eF2s[r1] = expf(0.01f*t2b);
    unsigned u;
    u = __float_as_uint(t1a); u = (u & 0x80000000u) ? ~u : (u | 0x80000000u);
    keys[r0] = ((unsigned long long)u << 32) | (unsigned)r0;
    u = __float_as_uint(t1b); u = (u & 0x80000000u) ? ~u : (u | 0x80000000u);
    keys[r1] = ((unsigned long long)u << 32) | (unsigned)r1;
    u = __float_as_uint(t2a); u = (u & 0x80000000u) ? ~u : (u | 0x80000000u);
    keys[NN + r0] = ((unsigned long long)u << 32) | (unsigned)r0;
    u = __float_as_uint(t2b); u = (u & 0x80000000u) ? ~u : (u | 0x80000000u);
    keys[NN + r1] = ((unsigned long long)u << 32) | (unsigned)r1;
  }
}

// ============ K2: rank counting — scan keys per-lane (coalesced), j-keys uniform (SGPR) ============
// grid 256 x 512: wave gw owns j's [gw*8, gw*8+8); arr = f1-keys for gw<1024, f2-keys after.
__global__ __launch_bounds__(512) void k_rank(
    const unsigned long long* __restrict__ keys,
    const float* __restrict__ f1, const float* __restrict__ E1,
    const float* __restrict__ E1s, const float* __restrict__ f2,
    float* __restrict__ s1, float* __restrict__ se1, float* __restrict__ se1s,
    float* __restrict__ f2s, int* __restrict__ rank2, int* __restrict__ inv)
{
  const int t = threadIdx.x;
  const int lane = t & 63, wv = t >> 6;        // 8 waves
  const int gw = blockIdx.x*8 + wv;            // 0..2047
  const int bj = gw*JW;                         // 0..16376
  const int arr = bj >> 13;                     // uniform per block (64-j aligned)
  const int jb = bj & (NN-1);
  const unsigned long long* kb = keys + ((size_t)arr << 13);
  // the wave's 8 j-keys as wave-uniform (SGPR) values
  unsigned long long K[JW];
#pragma unroll
  for (int q = 0; q < JW; ++q) {
    const unsigned long long kk = kb[jb + q];   // uniform address (one line)
    const unsigned lo = __builtin_amdgcn_readfirstlane((unsigned)kk);
    const unsigned hi = __builtin_amdgcn_readfirstlane((unsigned)(kk >> 32));
    K[q] = ((unsigned long long)hi << 32) | lo;
  }
  int cnt[JW];
#pragma unroll
  for (int q = 0; q < JW; ++q) cnt[q] = 0;
#pragma unroll 4
  for (int c = 0; c < NN/64; ++c) {
    const unsigned long long sk = kb[c*64 + lane];   // coalesced 512B wave-load
#pragma unroll
    for (int q = 0; q < JW; ++q)
      cnt[q] += (sk < K[q]) ? 1 : 0;                 // v_cmp_lt_u64 + addc
  }
#pragma unroll
  for (int q = 0; q < JW; ++q) {
    int r = cnt[q];
#pragma unroll
    for (int d = 1; d < 64; d <<= 1) r += __shfl_xor(r, d, 64);
    if (lane == 0) {
      const int i = jb + q;
      if (arr == 0) {
        s1[r] = f1[i]; se1[r] = E1[i]; se1s[r] = E1s[i];
      } else {
        rank2[i] = r; inv[r] = i; f2s[r] = f2[i];
      }
    }
  }
}

// ============ K3: per-block redundant chunk-prefix of sorted exp tables + D_j -> Bs/Es ============
// grid 256 x 1024: block b handles j in [32b, 32b+32)
__global__ __launch_bounds__(1024) void k_D(
    const float* __restrict__ se1, const float* __restrict__ se1s,
    const float* __restrict__ s1g, const float* __restrict__ f2,
    const float* __restrict__ eF2, const float* __restrict__ eF2s,
    const int* __restrict__ rank2,
    float* __restrict__ Bs, float* __restrict__ Es)
{
  __shared__ float s1l[NN];          // 32 KB
  __shared__ float csA[256], csB[256];
  __shared__ float csEA[257], csEB[257];
  const int t = threadIdx.x;
  const float4 a0 = ((const float4*)se1 )[t*2];
  const float4 a1v = ((const float4*)se1 )[t*2+1];
  const float4 b0 = ((const float4*)se1s)[t*2];
  const float4 b1v = ((const float4*)se1s)[t*2+1];
  ((float4*)s1l)[t*2]   = ((const float4*)s1g)[t*2];
  ((float4*)s1l)[t*2+1] = ((const float4*)s1g)[t*2+1];
  float sa = ((a0.x+a0.y)+(a0.z+a0.w)) + ((a1v.x+a1v.y)+(a1v.z+a1v.w));
  float sb = ((b0.x+b0.y)+(b0.z+b0.w)) + ((b1v.x+b1v.y)+(b1v.z+b1v.w));
  sa += __shfl_xor(sa, 1, 64); sb += __shfl_xor(sb, 1, 64);
  sa += __shfl_xor(sa, 2, 64); sb += __shfl_xor(sb, 2, 64);
  if ((t & 3) == 0) { csA[t>>2] = sa; csB[t>>2] = sb; }   // chunk(32) sums
  __syncthreads();
  for (int d = 1; d < 256; d <<= 1) {
    float pa = 0.f, pb = 0.f;
    if (t >= d && t < 256) { pa = csA[t-d]; pb = csB[t-d]; }
    __syncthreads();
    if (t < 256) { csA[t] += pa; csB[t] += pb; }
    __syncthreads();
  }
  if (t < 256) { csEA[t+1] = csA[t]; csEB[t+1] = csB[t]; }
  if (t == 0)  { csEA[0] = 0.f; csEB[0] = 0.f; }
  __syncthreads();
  const int wv = t >> 6, lane = t & 63;
  const int half = lane >> 5, m = lane & 31;
  const int j = blockIdx.x*32 + 2*wv + half;
  const float tgt = -f2[j];
  int pos = 0;
#pragma unroll
  for (int s = NN; s; s >>= 1) {
    const int c = pos + s;
    if (c <= NN && s1l[c-1] < tgt) pos = c;
  }
  const int base = pos & ~31, cnt = pos & 31;
  float ta = 0.f, tb = 0.f;
  if (m < cnt) { ta = se1[base+m]; tb = se1s[base+m]; }
#pragma unroll
  for (int d = 1; d < 32; d <<= 1) {
    ta += __shfl_xor(ta, d, 64);
    tb += __shfl_xor(tb, d, 64);
  }
  if (m == 0) {
    const float PreA = csEA[pos>>5] + ta;
    const float PreB = csEB[pos>>5] + tb;
    const float T1 = csEA[256];
    const float e2 = eF2[j], e2s = eF2s[j];
    const float D = fmaf(T1 - PreA, e2, PreB * e2s);
    const int r2 = rank2[j];
    Bs[r2] = e2 / D;
    Es[r2] = e2s / D;
  }
}

// ============ K4: chunk(32) column totals TU/TV (wave 0 -> U, wave 1 -> V) ============ grid 256 x 128
__global__ __launch_bounds__(128) void k_tuv(
    const float* __restrict__ seq, const int* __restrict__ inv,
    const float* __restrict__ Bs, const float* __restrict__ Es,
    float* __restrict__ TU, float* __restrict__ TV)
{
  const int c = blockIdx.x;
  const int h = threadIdx.x >> 6, o = threadIdx.x & 63;
  const float* __restrict__ S = h ? Es : Bs;
  float acc = 0.f;
#pragma unroll 8
  for (int m = 0; m < 32; ++m) {
    const int kk = c*32 + m;
    acc = fmaf(S[kk], seq[(size_t)inv[kk]*OO + o], acc);
  }
  (h ? TV : TU)[c*64 + o] = acc;
}

// ============ K5: PU/PV prefix rows (base = redundant TU/TV prefix) ============ grid 256 x 128
__global__ __launch_bounds__(128) void k_apply(
    const float* __restrict__ seq, const int* __restrict__ inv,
    const float* __restrict__ Bs, const float* __restrict__ Es,
    const float* __restrict__ TU, const float* __restrict__ TV,
    float* __restrict__ PU, float* __restrict__ PV)
{
  const int b = blockIdx.x;
  const int h = threadIdx.x >> 6, o = threadIdx.x & 63;
  const float* __restrict__ S = h ? Es : Bs;
  const float* __restrict__ T = h ? TV : TU;
  float* __restrict__ dst     = h ? PV : PU;
  float r = 0.f;
#pragma unroll 8
  for (int c = 0; c < b; ++c) r += T[c*64 + o];
#pragma unroll 4
  for (int k = 0; k < 32; ++k) {
    const int kk = b*32 + k;
    dst[(size_t)kk*OO + o] = r;
    r = fmaf(S[kk], seq[(size_t)inv[kk]*OO + o], r);
  }
  if (b == 255) dst[(size_t)NN*OO + o] = r;   // grand total row
}

// ============ K6: final combine + ELU (search in LDS-staged f2s) ============ grid 256 x 1024
__global__ __launch_bounds__(1024) void k_final(
    const float* __restrict__ f1, const float* __restrict__ E1,
    const float* __restrict__ E1s, const float* __restrict__ f2s,
    const float* __restrict__ PU, const float* __restrict__ PV,
    float* __restrict__ out)
{
  __shared__ float f2sl[NN];
  const int t = threadIdx.x;
  ((float4*)f2sl)[t*2]   = ((const float4*)f2s)[t*2];
  ((float4*)f2sl)[t*2+1] = ((const float4*)f2s)[t*2+1];
  __syncthreads();
  const int wv = t >> 6, lane = t & 63;
  const float utot = PU[(size_t)NN*OO + lane];
#pragma unroll
  for (int rr = 0; rr < 2; ++rr) {
    const int i = blockIdx.x*32 + 2*wv + rr;
    const float tgt = -f1[i];
    int pos = 0;
#pragma unroll
    for (int s = NN; s; s >>= 1) {
      const int c = pos + s;
      if (c <= NN && f2sl[c-1] < tgt) pos = c;
    }
    const float pu = PU[(size_t)pos*OO + lane];
    const float pv = PV[(size_t)pos*OO + lane];
    const float ret = E1[i]*(utot - pu) + E1s[i]*pv;
    out[(size_t)i*OO + lane] = (ret > 0.f) ? ret : expm1f(ret);
  }
}

extern "C" void kernel_launch(void* const* d_in, const int* in_sizes, int n_in,
                              void* d_out, int out_size, void* d_ws, size_t ws_size,
                              hipStream_t stream)
{
  (void)in_sizes; (void)n_in; (void)out_size; (void)ws_size;
  const float* x   = (const float*)d_in[0];
  const float* W1  = (const float*)d_in[1];
  const float* b1  = (const float*)d_in[2];
  const float* a1  = (const float*)d_in[3];
  const float* ba1 = (const float*)d_in[4];
  const float* a2  = (const float*)d_in[5];
  const float* ba2 = (const float*)d_in[6];
  float* out = (float*)d_out;

  float* w = (float*)d_ws;
  size_t off = 0;
  auto alloc = [&](size_t n) { float* p = w + off; off += (n + 63) & ~(size_t)63; return p; };
  float* seq  = alloc((size_t)NN*OO);
  float* f1   = alloc(NN);
  float* f2   = alloc(NN);
  float* E1   = alloc(NN);
  float* E1s  = alloc(NN);
  float* eF2  = alloc(NN);
  float* eF2s = alloc(NN);
  unsigned long long* keys = (unsigned long long*)alloc((size_t)4*NN);
  int*   rank2 = (int*)alloc(NN);
  int*   inv   = (int*)alloc(NN);
  float* s1   = alloc(NN);
  float* se1  = alloc(NN);
  float* se1s = alloc(NN);
  float* f2s  = alloc(NN);
  float* Bs   = alloc(NN);
  float* Es   = alloc(NN);
  float* TU   = alloc(256*64);
  float* TV   = alloc(256*64);
  float* PU   = alloc((size_t)(NN+1)*OO);
  float* PV   = alloc((size_t)(NN+1)*OO);

  k_gemm<<<512, 256, 0, stream>>>(x, W1, b1, a1, ba1, a2, ba2,
                                  seq, f1, f2, E1, E1s, eF2, eF2s, keys);
  k_rank<<<256, 512, 0, stream>>>(keys, f1, E1, E1s, f2,
                                  s1, se1, se1s, f2s, rank2, inv);
  k_D<<<256, 1024, 0, stream>>>(se1, se1s, s1, f2, eF2, eF2s, rank2, Bs, Es);
  k_tuv<<<256, 128, 0, stream>>>(seq, inv, Bs, Es, TU, TV);
  k_apply<<<256, 128, 0, stream>>>(seq, inv, Bs, Es, TU, TV, PU, PV);
  k_final<<<256, 1024, 0, stream>>>(f1, E1, E1s, f2s, PU, PV, out);
}